// Round 4
// baseline (135.806 us; speedup 1.0000x reference)
//
#include <hip/hip_runtime.h>
#include <hip/hip_bf16.h>
#include <stdint.h>

typedef __bf16  bf16x8 __attribute__((ext_vector_type(8)));
typedef __bf16  bf16x4 __attribute__((ext_vector_type(4)));
typedef float   f32x16 __attribute__((ext_vector_type(16)));
typedef uint32_t u32x4 __attribute__((ext_vector_type(4)));

#define SLEN  2048
#define DHEAD 128
#define QBLK  128          // 4 waves x 32 q-rows
#define KVBLK 64
#define NQT   (SLEN / QBLK) // 16
#define THR   8.0f

// XOR swizzle, 16B granularity: mixes low AND high row bits so both the
// row-varying reads and the high-bit-varying transposed writes spread banks.
__device__ __forceinline__ int swz8(int row) {
    return (((row & 7) ^ ((row >> 3) & 7)) << 4);
}
#define KROW(reg) ((((reg) & 3) + 8 * ((reg) >> 2)) + 4 * hi)

__device__ __forceinline__ uint32_t cvt_pk(float lo, float hi2) {
    uint32_t u;
    asm("v_cvt_pk_bf16_f32 %0, %1, %2" : "=v"(u) : "v"(lo), "v"(hi2));
    return u;
}

__global__ __launch_bounds__(256, 2) void attn_fwd(
    const float* __restrict__ Q, const float* __restrict__ K,
    const float* __restrict__ V, float* __restrict__ O)
{
    const int bh = blockIdx.x;              // heads fastest
    const int qb = (NQT - 1) - blockIdx.y;  // LPT: longest first
    const int tid  = threadIdx.x;
    const int w    = tid >> 6;
    const int lane = tid & 63;
    const int c    = lane & 31;   // q-col (B) / kv-row (A) / d-col (PV B)
    const int hi   = lane >> 5;

    const size_t head_off = (size_t)bh * SLEN * DHEAD;
    const float* Qh = Q + head_off;
    const float* Kh = K + head_off;
    const float* Vh = V + head_off;
    float*       Oh = O + head_off;

    const int q0w = qb * QBLK + w * 32;     // wave's first q row

    __shared__ __bf16 K_sh [2][KVBLK * DHEAD]; // [64][128] rows 256B
    __shared__ __bf16 Vt_sh[2][DHEAD * KVBLK]; // [128][64] rows 128B (row=d)

    const float scale = 0.08838834764831845f;

    // ---- Q fragments (B operand): col=q0w+c, k(d) = ks*16 + hi*8 + e ----
    bf16x8 qfrag[8];
    {
        const float* qrow = Qh + (size_t)(q0w + c) * DHEAD;
        #pragma unroll
        for (int ks = 0; ks < 8; ++ks) {
            const int d0 = ks * 16 + hi * 8;
            float4 a = *reinterpret_cast<const float4*>(qrow + d0);
            float4 b = *reinterpret_cast<const float4*>(qrow + d0 + 4);
            a.x*=scale; a.y*=scale; a.z*=scale; a.w*=scale;
            b.x*=scale; b.y*=scale; b.z*=scale; b.w*=scale;
            bf16x8 f;
            f[0]=(__bf16)a.x; f[1]=(__bf16)a.y; f[2]=(__bf16)a.z; f[3]=(__bf16)a.w;
            f[4]=(__bf16)b.x; f[5]=(__bf16)b.y; f[6]=(__bf16)b.z; f[7]=(__bf16)b.w;
            qfrag[ks] = f;
        }
    }

    // staging registers (in flight across compute)
    float4 kreg[8], vreg[8];
    const int c4  = tid & 31;       // K: float4 col
    const int dm  = tid & 15;       // V: d-slice (8 d's)
    const int kvq = tid >> 4;       // V: kv quad (4 rows)

    auto issue_loads = [&](int kv0) {
        #pragma unroll
        for (int it = 0; it < 8; ++it) {
            const int row = (it * 256 + tid) >> 5;
            kreg[it] = *reinterpret_cast<const float4*>(
                Kh + (size_t)(kv0 + row) * DHEAD + c4 * 4);
        }
        #pragma unroll
        for (int kr = 0; kr < 4; ++kr) {
            const float* vrow = Vh + (size_t)(kv0 + kvq * 4 + kr) * DHEAD + dm * 8;
            vreg[kr*2    ] = *reinterpret_cast<const float4*>(vrow);
            vreg[kr*2 + 1] = *reinterpret_cast<const float4*>(vrow + 4);
        }
    };

    auto write_tiles = [&](int buf) {
        char* Kb  = reinterpret_cast<char*>(K_sh[buf]);
        char* Vtb = reinterpret_cast<char*>(Vt_sh[buf]);
        #pragma unroll
        for (int it = 0; it < 8; ++it) {
            const int idx = it * 256 + tid;
            const int row = idx >> 5;
            bf16x4 k4;
            k4[0]=(__bf16)kreg[it].x; k4[1]=(__bf16)kreg[it].y;
            k4[2]=(__bf16)kreg[it].z; k4[3]=(__bf16)kreg[it].w;
            *reinterpret_cast<bf16x4*>(
                Kb + row * 256 + ((c4 * 8) ^ swz8(row))) = k4;
        }
        #pragma unroll
        for (int j = 0; j < 8; ++j) {
            const int d = dm * 8 + j;
            bf16x4 v4;
            #pragma unroll
            for (int kr = 0; kr < 4; ++kr)
                v4[kr] = (__bf16)((&vreg[kr*2 + (j>>2)].x)[j & 3]);
            *reinterpret_cast<bf16x4*>(
                Vtb + d * 128 + ((kvq * 8) ^ swz8(d))) = v4;
        }
    };

    f32x16 acc_o[4];
    #pragma unroll
    for (int dt = 0; dt < 4; ++dt)
        #pragma unroll
        for (int i = 0; i < 16; ++i) acc_o[dt][i] = 0.f;
    float m_run = -1e30f, l_run = 0.f;

    issue_loads(0);
    write_tiles(0);

    const int kvt_blk_max = 2 * qb + 1;
    const int kvt_max_w   = (q0w + 31) >> 6;
    int cur = 0;

    for (int kvt = 0; kvt <= kvt_blk_max; ++kvt) {
        __syncthreads();
        const bool more = (kvt < kvt_blk_max);
        if (more) issue_loads((kvt + 1) * KVBLK);

        if (kvt <= kvt_max_w) {
            const int kv0 = kvt * KVBLK;
            char* Kb  = reinterpret_cast<char*>(K_sh[cur]);
            char* Vtb = reinterpret_cast<char*>(Vt_sh[cur]);

            const bool alive1 = (kv0 + 32 <= q0w + 31);

            // ---- swapped QK^T: S^T[kv][q], two 32-kv tiles ----
            f32x16 st[2];
            __builtin_amdgcn_s_setprio(1);
            #pragma unroll
            for (int t = 0; t < 2; ++t) {
                if (t == 1 && !alive1) break;
                #pragma unroll
                for (int i = 0; i < 16; ++i) st[t][i] = 0.f;
                const int krow = t * 32 + c;
                #pragma unroll
                for (int ks = 0; ks < 8; ++ks) {
                    bf16x8 kf = *reinterpret_cast<const bf16x8*>(
                        Kb + krow * 256 + ((ks*32 + hi*16) ^ swz8(krow)));
                    st[t] = __builtin_amdgcn_mfma_f32_32x32x16_bf16(
                        kf, qfrag[ks], st[t], 0, 0, 0);
                }
            }
            __builtin_amdgcn_s_setprio(0);

            // ---- mask + in-register online softmax (lane owns q=q0w+c) ----
            const int q = q0w + c;
            float pmax = -1e30f;
            #pragma unroll
            for (int t = 0; t < 2; ++t) {
                if (t == 1 && !alive1) break;
                if (kv0 + t*32 + 31 > q0w) {   // diag region: mask
                    #pragma unroll
                    for (int reg = 0; reg < 16; ++reg)
                        if (kv0 + t*32 + KROW(reg) > q) st[t][reg] = -1e30f;
                }
                #pragma unroll
                for (int reg = 0; reg < 16; ++reg)
                    pmax = fmaxf(pmax, st[t][reg]);
            }
            pmax = fmaxf(pmax, __shfl_xor(pmax, 32));

            if (__any(pmax > m_run + THR)) {   // rare (defer-max)
                const float m_new = fmaxf(m_run, pmax);
                const float corr  = __expf(m_run - m_new);
                l_run *= corr; m_run = m_new;
                #pragma unroll
                for (int reg = 0; reg < 16; ++reg) {
                    const float cr = __shfl(corr, KROW(reg));
                    #pragma unroll
                    for (int dt = 0; dt < 4; ++dt) acc_o[dt][reg] *= cr;
                }
            }

            float rowsum = 0.f;
            #pragma unroll
            for (int t = 0; t < 2; ++t) {
                if (t == 1 && !alive1) break;
                #pragma unroll
                for (int reg = 0; reg < 16; ++reg) {
                    const float p = __expf(st[t][reg] - m_run);
                    st[t][reg] = p;
                    rowsum += p;
                }
            }
            rowsum += __shfl_xor(rowsum, 32);
            l_run += rowsum;

            // ---- P redistribute (cvt_pk + shfl_xor 32) + PV ----
            #pragma unroll
            for (int ks = 0; ks < 4; ++ks) {
                if (kv0 + ks*16 > q0w + 31) break;  // dead k-slice
                const int t = ks >> 1, k1 = (ks & 1) * 8;
                const uint32_t pkA0 = cvt_pk(st[t][k1+0], st[t][k1+1]);
                const uint32_t pkA1 = cvt_pk(st[t][k1+2], st[t][k1+3]);
                const uint32_t pkB0 = cvt_pk(st[t][k1+4], st[t][k1+5]);
                const uint32_t pkB1 = cvt_pk(st[t][k1+6], st[t][k1+7]);
                const uint32_t rA0 = (uint32_t)__shfl_xor((int)pkA0, 32);
                const uint32_t rA1 = (uint32_t)__shfl_xor((int)pkA1, 32);
                const uint32_t rB0 = (uint32_t)__shfl_xor((int)pkB0, 32);
                const uint32_t rB1 = (uint32_t)__shfl_xor((int)pkB1, 32);
                u32x4 words;
                words[0] = hi ? rB0 : pkA0;
                words[1] = hi ? rB1 : pkA1;
                words[2] = hi ? pkB0 : rA0;
                words[3] = hi ? pkB1 : rA1;
                const bf16x8 pa = __builtin_bit_cast(bf16x8, words);
                __builtin_amdgcn_s_setprio(1);
                #pragma unroll
                for (int dt = 0; dt < 4; ++dt) {
                    const int d = dt * 32 + c;
                    bf16x8 vf = *reinterpret_cast<const bf16x8*>(
                        Vtb + d * 128 + ((ks*32 + hi*16) ^ swz8(d)));
                    acc_o[dt] = __builtin_amdgcn_mfma_f32_32x32x16_bf16(
                        pa, vf, acc_o[dt], 0, 0, 0);
                }
                __builtin_amdgcn_s_setprio(0);
            }
        }

        if (more) write_tiles(cur ^ 1);
        cur ^= 1;
    }

    // ---- epilogue: O[q0w+KROW][dt*32+c] = acc / l ----
    const float inv = 1.0f / l_run;
    #pragma unroll
    for (int reg = 0; reg < 16; ++reg) {
        const float iv = __shfl(inv, KROW(reg));
        float* orow = Oh + (size_t)(q0w + KROW(reg)) * DHEAD + c;
        #pragma unroll
        for (int dt = 0; dt < 4; ++dt)
            orow[dt * 32] = acc_o[dt][reg] * iv;
    }
}

extern "C" void kernel_launch(void* const* d_in, const int* in_sizes, int n_in,
                              void* d_out, int out_size, void* d_ws, size_t ws_size,
                              hipStream_t stream) {
    const float* Q = (const float*)d_in[0];
    const float* K = (const float*)d_in[1];
    const float* V = (const float*)d_in[2];
    float* O = (float*)d_out;
    dim3 grid(32 /* B*H */, NQT);
    attn_fwd<<<grid, 256, 0, stream>>>(Q, K, V, O);
}

// Round 5
// 92.455 us; speedup vs baseline: 1.4689x; 1.4689x over previous
//
#include <hip/hip_runtime.h>
#include <hip/hip_bf16.h>
#include <stdint.h>

typedef __bf16  bf16x8 __attribute__((ext_vector_type(8)));
typedef __bf16  bf16x4 __attribute__((ext_vector_type(4)));
typedef float   f32x4  __attribute__((ext_vector_type(4)));
typedef uint32_t u32x4 __attribute__((ext_vector_type(4)));

#define SLEN  2048
#define DHEAD 128
#define QBLK  64            // 4 waves x 16 q-rows
#define KVBLK 32
#define NQT   (SLEN / QBLK) // 32
#define THR   8.0f
#define VSTR  40            // Vt row stride in bf16 (80B): banks 20d%32 -> 2-way

__device__ __forceinline__ uint32_t cvt_pk(float lo, float hi2) {
    uint32_t u;
    asm("v_cvt_pk_bf16_f32 %0, %1, %2" : "=v"(u) : "v"(lo), "v"(hi2));
    return u;
}

__global__ __launch_bounds__(256, 3) void attn_fwd(
    const float* __restrict__ Q, const float* __restrict__ K,
    const float* __restrict__ V, float* __restrict__ O)
{
    const int bh = blockIdx.x;              // heads fastest
    const int qt = (NQT - 1) - blockIdx.y;  // LPT: longest first
    const int tid  = threadIdx.x;
    const int w    = tid >> 6;
    const int lane = tid & 63;
    const int r    = lane & 15;
    const int g    = lane >> 4;

    const size_t head_off = (size_t)bh * SLEN * DHEAD;
    const float* Qh = Q + head_off;
    const float* Kh = K + head_off;
    const float* Vh = V + head_off;
    float*       Oh = O + head_off;

    const int q0w = qt * QBLK + w * 16;     // wave's first q row

    __shared__ __bf16 K_sh [2][KVBLK * DHEAD];  // [32][128] rows 256B, swz (row&15)<<4
    __shared__ __bf16 Vt_sh[2][DHEAD * VSTR];   // [128][40] rows 80B, quad-xor swz

    const float scale = 0.08838834764831845f;

    // ---- Q fragments (B operand): col=q0w+r, k = kb*32 + g*8 + e ----
    bf16x8 qfrag[4];
    {
        const float4* qp = reinterpret_cast<const float4*>(
            Qh + (size_t)(q0w + r) * DHEAD + g * 8);
        #pragma unroll
        for (int kb = 0; kb < 4; ++kb) {
            float4 a = qp[kb*8 + 0];
            float4 b = qp[kb*8 + 1];
            a.x*=scale; a.y*=scale; a.z*=scale; a.w*=scale;
            b.x*=scale; b.y*=scale; b.z*=scale; b.w*=scale;
            bf16x8 f;
            f[0]=(__bf16)a.x; f[1]=(__bf16)a.y; f[2]=(__bf16)a.z; f[3]=(__bf16)a.w;
            f[4]=(__bf16)b.x; f[5]=(__bf16)b.y; f[6]=(__bf16)b.z; f[7]=(__bf16)b.w;
            qfrag[kb] = f;
        }
    }

    // staging regs
    float4 kreg[4], vreg[4];
    const int c4  = tid & 31;
    const int kvq = tid >> 5;        // 0..7: V kv-quad

    auto issue_loads = [&](int kv0) {
        #pragma unroll
        for (int it = 0; it < 4; ++it) {
            const int row = (it * 256 + tid) >> 5;
            kreg[it] = *reinterpret_cast<const float4*>(
                Kh + (size_t)(kv0 + row) * DHEAD + c4 * 4);
        }
        #pragma unroll
        for (int kr = 0; kr < 4; ++kr)
            vreg[kr] = *reinterpret_cast<const float4*>(
                Vh + (size_t)(kv0 + kvq * 4 + kr) * DHEAD + c4 * 4);
    };

    auto write_tiles = [&](int buf) {
        char* Kb  = reinterpret_cast<char*>(K_sh[buf]);
        char* Vtb = reinterpret_cast<char*>(Vt_sh[buf]);
        #pragma unroll
        for (int it = 0; it < 4; ++it) {
            const int row = (it * 256 + tid) >> 5;
            bf16x4 k4;
            k4[0]=(__bf16)kreg[it].x; k4[1]=(__bf16)kreg[it].y;
            k4[2]=(__bf16)kreg[it].z; k4[3]=(__bf16)kreg[it].w;
            *reinterpret_cast<bf16x4*>(
                Kb + row * 256 + ((c4 * 8) ^ ((row & 15) << 4))) = k4;
        }
        #pragma unroll
        for (int j = 0; j < 4; ++j) {
            const int d = c4 * 4 + j;
            bf16x4 v4;
            #pragma unroll
            for (int kr = 0; kr < 4; ++kr)
                v4[kr] = (__bf16)((&vreg[kr].x)[j]);
            // quad kvq placed at slot kvq ^ ((d>>2)&6)  (even xor keeps pairs)
            *reinterpret_cast<bf16x4*>(
                Vtb + d * 80 + ((kvq ^ ((d >> 2) & 6)) * 8)) = v4;
        }
    };

    const f32x4 vzero = {0.f, 0.f, 0.f, 0.f};
    f32x4 acc_o[8];
    #pragma unroll
    for (int i = 0; i < 8; ++i) acc_o[i] = vzero;
    float m_run = -1e30f, l_run = 0.f;

    issue_loads(0);
    write_tiles(0);

    const int kvt_blk_max = 2 * qt + 1;
    const int kvt_max_w   = (q0w + 15) >> 5;
    int cur = 0;

    for (int kvt = 0; kvt <= kvt_blk_max; ++kvt) {
        __syncthreads();
        const bool more = (kvt < kvt_blk_max);
        if (more) issue_loads((kvt + 1) * KVBLK);

        if (kvt <= kvt_max_w) {
            const int kv0 = kvt * KVBLK;
            char* Kb  = reinterpret_cast<char*>(K_sh[cur]);
            char* Vtb = reinterpret_cast<char*>(Vt_sh[cur]);

            const bool alive1 = (kv0 + 16 <= q0w + 15);

            // ---- swapped QK^T: S^T[kv][q]; lane owns q = q0w + r ----
            // A=K: row = t*16 + r, k = kb*32 + g*8 + e
            f32x4 st[2] = {vzero, vzero};
            __builtin_amdgcn_s_setprio(1);
            #pragma unroll
            for (int t = 0; t < 2; ++t) {
                if (t == 1 && !alive1) break;
                const int row = t * 16 + r;
                #pragma unroll
                for (int kb = 0; kb < 4; ++kb) {
                    bf16x8 kf = *reinterpret_cast<const bf16x8*>(
                        Kb + row * 256 + ((kb*64 + g*16) ^ ((row & 15) << 4)));
                    st[t] = __builtin_amdgcn_mfma_f32_16x16x32_bf16(
                        kf, qfrag[kb], st[t], 0, 0, 0);
                }
            }
            __builtin_amdgcn_s_setprio(0);

            // ---- mask (lane's kv = kv0 + t*16 + 4g + j; q = q0w + r) ----
            const int q = q0w + r;
            float pmax = -1e30f;
            #pragma unroll
            for (int t = 0; t < 2; ++t) {
                if (t == 1 && !alive1) break;
                if (kv0 + t*16 + 15 > q0w) {
                    #pragma unroll
                    for (int j = 0; j < 4; ++j)
                        if (kv0 + t*16 + 4*g + j > q) st[t][j] = -1e30f;
                }
                #pragma unroll
                for (int j = 0; j < 4; ++j) pmax = fmaxf(pmax, st[t][j]);
            }
            pmax = fmaxf(pmax, __shfl_xor(pmax, 16));
            pmax = fmaxf(pmax, __shfl_xor(pmax, 32));

            if (__any(pmax > m_run + THR)) {   // rare (defer-max)
                const float m_new = fmaxf(m_run, pmax);
                const float corr  = __expf(m_run - m_new);
                l_run *= corr; m_run = m_new;
                #pragma unroll
                for (int reg = 0; reg < 4; ++reg) {
                    const float cr = __shfl(corr, 4*g + reg); // acc q = q0w+4g+reg
                    #pragma unroll
                    for (int dt = 0; dt < 8; ++dt) acc_o[dt][reg] *= cr;
                }
            }

            float rowsum = 0.f;
            #pragma unroll
            for (int t = 0; t < 2; ++t) {
                if (t == 1 && !alive1) break;
                #pragma unroll
                for (int j = 0; j < 4; ++j) {
                    const float p = __expf(st[t][j] - m_run);
                    st[t][j] = p;
                    rowsum += p;
                }
            }
            rowsum += __shfl_xor(rowsum, 16);
            rowsum += __shfl_xor(rowsum, 32);
            l_run += rowsum;

            // ---- P redistribute: A-frag k = g*8+e; word w from lane
            //      2(g&1)+(w>>1), tile g>>1, pk pair (w&1) ----
            const uint32_t p00 = cvt_pk(st[0][0], st[0][1]);
            const uint32_t p01 = cvt_pk(st[0][2], st[0][3]);
            const uint32_t p10 = alive1 ? cvt_pk(st[1][0], st[1][1]) : 0u;
            const uint32_t p11 = alive1 ? cvt_pk(st[1][2], st[1][3]) : 0u;
            const int sA = r + ((2 * (g & 1)) << 4);      // w = 0,1
            const int sB = r + ((2 * (g & 1) + 1) << 4);  // w = 2,3
            u32x4 words;
            {
                const uint32_t lo0 = (uint32_t)__shfl((int)p00, sA);
                const uint32_t hi0 = (uint32_t)__shfl((int)p10, sA);
                const uint32_t lo1 = (uint32_t)__shfl((int)p01, sA);
                const uint32_t hi1 = (uint32_t)__shfl((int)p11, sA);
                const uint32_t lo2 = (uint32_t)__shfl((int)p00, sB);
                const uint32_t hi2 = (uint32_t)__shfl((int)p10, sB);
                const uint32_t lo3 = (uint32_t)__shfl((int)p01, sB);
                const uint32_t hi3 = (uint32_t)__shfl((int)p11, sB);
                words[0] = (g & 2) ? hi0 : lo0;
                words[1] = (g & 2) ? hi1 : lo1;
                words[2] = (g & 2) ? hi2 : lo2;
                words[3] = (g & 2) ? hi3 : lo3;
            }
            const bf16x8 pa = __builtin_bit_cast(bf16x8, words);

            // ---- PV: B = Vt[d = dt*16 + r][kv = g*8 .. g*8+7] ----
            __builtin_amdgcn_s_setprio(1);
            #pragma unroll
            for (int dt = 0; dt < 8; ++dt) {
                const int d = dt * 16 + r;
                bf16x8 vf = *reinterpret_cast<const bf16x8*>(
                    Vtb + d * 80 + (((2*g) ^ ((d >> 2) & 6)) * 8));
                acc_o[dt] = __builtin_amdgcn_mfma_f32_16x16x32_bf16(
                    pa, vf, acc_o[dt], 0, 0, 0);
            }
            __builtin_amdgcn_s_setprio(0);
        }

        if (more) write_tiles(cur ^ 1);
        cur ^= 1;
    }

    // ---- epilogue: O[q0w + 4g + reg][dt*16 + r] = acc / l ----
    const float inv = 1.0f / l_run;
    #pragma unroll
    for (int reg = 0; reg < 4; ++reg) {
        const float iv = __shfl(inv, 4*g + reg);
        float* orow = Oh + (size_t)(q0w + 4*g + reg) * DHEAD + r;
        #pragma unroll
        for (int dt = 0; dt < 8; ++dt)
            orow[dt * 16] = acc_o[dt][reg] * iv;
    }
}

extern "C" void kernel_launch(void* const* d_in, const int* in_sizes, int n_in,
                              void* d_out, int out_size, void* d_ws, size_t ws_size,
                              hipStream_t stream) {
    const float* Q = (const float*)d_in[0];
    const float* K = (const float*)d_in[1];
    const float* V = (const float*)d_in[2];
    float* O = (float*)d_out;
    dim3 grid(32 /* B*H */, NQT);
    attn_fwd<<<grid, 256, 0, stream>>>(Q, K, V, O);
}